// Round 17
// baseline (756.112 us; speedup 1.0000x reference)
//
#include <hip/hip_runtime.h>
#include <math.h>

#define BB 512
#define SS 50
#define EE 128
#define HH 8
#define RR 32
#define NC 5
#define NSEQ 20000
#define NBS (BB*SS)   // 25600
#define LDK 136       // padded bf16 row stride (ushorts) for LDS A-tile
#define ATTN_REP 12   // measurement: attn dispatch dur = 12 * T_attn
#define REG_REP 3     // measurement: region dispatch dur = 3 * T_region (hoist-defeated)

typedef __attribute__((ext_vector_type(8))) __bf16 bf16x8;
typedef __attribute__((ext_vector_type(4))) float f32x4;
typedef __attribute__((ext_vector_type(4))) unsigned short us4;

__device__ __forceinline__ unsigned short f2bf(float f) {
    unsigned int u = __float_as_uint(f);
    unsigned int r = (u + 0x7fffu + ((u >> 16) & 1u)) >> 16;
    return (unsigned short)r;
}
__device__ __forceinline__ float bf2f(unsigned short s) {
    return __uint_as_float(((unsigned int)s) << 16);
}
__device__ __forceinline__ float dot4v(const f32x4& a, const float4& b) {
    return a[0]*b.x + a[1]*b.y + a[2]*b.z + a[3]*b.w;
}

// -------------------- prep: weight transposes/copies + seq histogram --------------------
__global__ __launch_bounds__(256) void prep_kernel(const float* __restrict__ wv,
                                                   const float* __restrict__ wo,
                                                   const float* __restrict__ wq,
                                                   const float* __restrict__ wk,
                                                   unsigned short* __restrict__ wvT,
                                                   unsigned short* __restrict__ woT,
                                                   unsigned short* __restrict__ wqB,
                                                   unsigned short* __restrict__ wkB,
                                                   const int* __restrict__ seq,
                                                   int* __restrict__ hist) {
    const int bid = blockIdx.x, t = threadIdx.x;
    if (bid < 128) {
        const int n = bid;
        if (t < 128) wvT[n*EE + t] = f2bf(wv[t*EE + n]);
        else         woT[n*EE + (t - 128)] = f2bf(wo[(t - 128)*EE + n]);
    } else if (bid < 192) {
        const int idx = (bid - 128) * 256 + t;   // 64*256 = 16384 = EE*EE
        wqB[idx] = f2bf(wq[idx]);
        wkB[idx] = f2bf(wk[idx]);
    } else {
        const int i = (bid - 192) * 256 + t;
        if (i < NBS) atomicAdd(&hist[seq[i]], 1);
    }
}

// -------------------- scan + scatter (counting sort by seq) --------------------
__global__ __launch_bounds__(1024) void scan_kernel(int* __restrict__ hist,
                                                    int* __restrict__ hstart) {
    const int t = threadIdx.x;
    const int CH = 20;
    const int base = t * CH;
    int loc[CH];
    int s = 0;
    #pragma unroll
    for (int i = 0; i < CH; ++i) {
        int idx = base + i;
        int v = (idx < NSEQ) ? hist[idx] : 0;
        loc[i] = s; s += v;
    }
    const int lane = t & 63, w = t >> 6;
    int incl = s;
    #pragma unroll
    for (int off = 1; off < 64; off <<= 1) {
        int n = __shfl_up(incl, off);
        if (lane >= off) incl += n;
    }
    __shared__ int wsum[16];
    if (lane == 63) wsum[w] = incl;
    __syncthreads();
    if (t == 0) {
        int acc = 0;
        #pragma unroll
        for (int k = 0; k < 16; ++k) { int v = wsum[k]; wsum[k] = acc; acc += v; }
    }
    __syncthreads();
    const int excl = incl - s + wsum[w];
    #pragma unroll
    for (int i = 0; i < CH; ++i) {
        int idx = base + i;
        if (idx < NSEQ) {
            int e = excl + loc[i];
            hist[idx] = e;
            hstart[idx] = e;
        }
    }
    if (t == 0) hstart[NSEQ] = NBS;
}

__global__ __launch_bounds__(256) void scatter_kernel(const int* __restrict__ seq,
                                                      int* __restrict__ hist,
                                                      int* __restrict__ perm) {
    int i = blockIdx.x * 256 + threadIdx.x;
    if (i < NBS) {
        int pos = atomicAdd(&hist[seq[i]], 1);
        perm[pos] = i;
    }
}

// -------------------- Kernel 1: attention (r16 verified), ATTN_REP measurement loop -----
__global__ __launch_bounds__(1024, 8) void attn_kernel(
    const int* __restrict__ user,
    const int* __restrict__ neighbor,
    const float* __restrict__ uet,
    const unsigned short* __restrict__ wqB, const float* __restrict__ bq,
    const unsigned short* __restrict__ wkB, const float* __restrict__ bk,
    const float* __restrict__ bv, const float* __restrict__ bo,
    const unsigned short* __restrict__ wvT, const unsigned short* __restrict__ woT,
    float* __restrict__ ws_ne2)
{
    __shared__ unsigned short kA[64*LDK];
    __shared__ unsigned short qkvT[16][EE];
    __shared__ float ue[EE];
    __shared__ float qs[EE];
    __shared__ float qkb[HH];
    __shared__ float attn_s[HH][64];
    __shared__ float maskadd[64];

    const int b = blockIdx.x;
    const int t = threadIdx.x;

    for (int rep = 0; rep < ATTN_REP; ++rep) {

    if (t < EE) ue[t] = uet[(size_t)user[b]*EE + t];
    if (t >= 128 && t < 192) {
        const int s = t - 128;
        const bool real = (s < SS) && (neighbor[b*SS + s] > 0);
        maskadd[s] = real ? 0.f : -1e9f;
    }
    for (int idx = t; idx < SS*32; idx += 1024) {
        int s = idx >> 5, g = idx & 31;
        float4 v = ((const float4*)(uet + (size_t)neighbor[b*SS + s]*EE))[g];
        us4 o; o.x = f2bf(v.x); o.y = f2bf(v.y); o.z = f2bf(v.z); o.w = f2bf(v.w);
        *(us4*)&kA[s*LDK + g*4] = o;
    }
    for (int idx = t; idx < 14*LDK; idx += 1024) kA[50*LDK + idx] = 0;
    if (t < 8*EE) qkvT[8 + (t >> 7)][t & 127] = 0;
    __syncthreads();

    {
        const int col = t >> 3, sub = t & 7;
        float acc = 0.f;
        #pragma unroll
        for (int d = 0; d < 16; ++d)
            acc = fmaf(ue[sub*16 + d], bf2f(wqB[(sub*16 + d)*EE + col]), acc);
        acc += __shfl_xor(acc, 1);
        acc += __shfl_xor(acc, 2);
        acc += __shfl_xor(acc, 4);
        if (sub == 0) qs[col] = acc + bq[col];
    }
    __syncthreads();

    {
        const int e = t >> 3, h = t & 7;
        const unsigned short* wrow = wkB + (size_t)e*EE + h*16;
        float acc = 0.f;
        #pragma unroll
        for (int d = 0; d < 16; ++d)
            acc = fmaf(qs[h*16 + d], bf2f(wrow[d]), acc);
        qkvT[h][e] = f2bf(acc);
    }
    if (t < HH) {
        float acc = 0.f;
        #pragma unroll
        for (int d = 0; d < 16; ++d) acc = fmaf(qs[t*16 + d], bk[t*16 + d], acc);
        qkb[t] = acc;
    }
    __syncthreads();

    const int w    = t >> 6;
    const int l    = t & 63;
    const int lrow = l & 15;
    const int kg   = l >> 4;
    const int rt   = w & 3;
    const int np   = w >> 2;

    bf16x8 a0 = *(const bf16x8*)&kA[(rt*16 + lrow)*LDK +  0 + kg*8];
    bf16x8 a1 = *(const bf16x8*)&kA[(rt*16 + lrow)*LDK + 32 + kg*8];
    bf16x8 a2 = *(const bf16x8*)&kA[(rt*16 + lrow)*LDK + 64 + kg*8];
    bf16x8 a3 = *(const bf16x8*)&kA[(rt*16 + lrow)*LDK + 96 + kg*8];

    if (np == 0) {
        bf16x8 b0 = *(const bf16x8*)&qkvT[lrow][ 0 + kg*8];
        bf16x8 b1 = *(const bf16x8*)&qkvT[lrow][32 + kg*8];
        bf16x8 b2 = *(const bf16x8*)&qkvT[lrow][64 + kg*8];
        bf16x8 b3 = *(const bf16x8*)&qkvT[lrow][96 + kg*8];
        f32x4 c = {0.f, 0.f, 0.f, 0.f};
        c = __builtin_amdgcn_mfma_f32_16x16x32_bf16(a0, b0, c, 0, 0, 0);
        c = __builtin_amdgcn_mfma_f32_16x16x32_bf16(a1, b1, c, 0, 0, 0);
        c = __builtin_amdgcn_mfma_f32_16x16x32_bf16(a2, b2, c, 0, 0, 0);
        c = __builtin_amdgcn_mfma_f32_16x16x32_bf16(a3, b3, c, 0, 0, 0);
        const int h = lrow;
        if (h < HH) {
            #pragma unroll
            for (int rg = 0; rg < 4; ++rg) {
                const int row = rt*16 + kg*4 + rg;
                attn_s[h][row] = (c[rg] + qkb[h]) * 0.25f + maskadd[row];
            }
        }
    }
    __syncthreads();

    if (t < 64) {
        int h = t >> 3, ll = t & 7;
        float mx = -3e38f;
        #pragma unroll
        for (int i = 0; i < 7; ++i) { int s = i*8 + ll; if (s < SS) mx = fmaxf(mx, attn_s[h][s]); }
        mx = fmaxf(mx, __shfl_xor(mx, 1));
        mx = fmaxf(mx, __shfl_xor(mx, 2));
        mx = fmaxf(mx, __shfl_xor(mx, 4));
        float ev[7]; float sm_ = 0.f;
        #pragma unroll
        for (int i = 0; i < 7; ++i) {
            int s = i*8 + ll; ev[i] = 0.f;
            if (s < SS) { ev[i] = expf(attn_s[h][s] - mx); sm_ += ev[i]; }
        }
        sm_ += __shfl_xor(sm_, 1);
        sm_ += __shfl_xor(sm_, 2);
        sm_ += __shfl_xor(sm_, 4);
        float inv = 1.f / sm_;
        #pragma unroll
        for (int i = 0; i < 7; ++i) { int s = i*8 + ll; if (s < SS) attn_s[h][s] = ev[i] * inv; }
    }
    __syncthreads();

    #pragma unroll
    for (int q = 0; q < 2; ++q) {
        const int nt = np*2 + q;
        const unsigned short* bp = wvT + (nt*16 + lrow)*EE + kg*8;
        bf16x8 b0 = *(const bf16x8*)&bp[0];
        bf16x8 b1 = *(const bf16x8*)&bp[32];
        bf16x8 b2 = *(const bf16x8*)&bp[64];
        bf16x8 b3 = *(const bf16x8*)&bp[96];
        f32x4 c = {0.f, 0.f, 0.f, 0.f};
        c = __builtin_amdgcn_mfma_f32_16x16x32_bf16(a0, b0, c, 0, 0, 0);
        c = __builtin_amdgcn_mfma_f32_16x16x32_bf16(a1, b1, c, 0, 0, 0);
        c = __builtin_amdgcn_mfma_f32_16x16x32_bf16(a2, b2, c, 0, 0, 0);
        c = __builtin_amdgcn_mfma_f32_16x16x32_bf16(a3, b3, c, 0, 0, 0);
        const int col = nt*16 + lrow;
        const float bvc = bv[col];
        #pragma unroll
        for (int rg = 0; rg < 4; ++rg) {
            const int row = rt*16 + kg*4 + rg;
            const float av = (row < SS) ? attn_s[nt][row] : 0.f;
            kA[row*LDK + col] = f2bf((c[rg] + bvc) * av);
        }
    }
    __syncthreads();

    bf16x8 c0 = *(const bf16x8*)&kA[(rt*16 + lrow)*LDK +  0 + kg*8];
    bf16x8 c1 = *(const bf16x8*)&kA[(rt*16 + lrow)*LDK + 32 + kg*8];
    bf16x8 c2 = *(const bf16x8*)&kA[(rt*16 + lrow)*LDK + 64 + kg*8];
    bf16x8 c3 = *(const bf16x8*)&kA[(rt*16 + lrow)*LDK + 96 + kg*8];

    #pragma unroll
    for (int q = 0; q < 2; ++q) {
        const int nt = np*2 + q;
        const unsigned short* bp = woT + (nt*16 + lrow)*EE + kg*8;
        bf16x8 b0 = *(const bf16x8*)&bp[0];
        bf16x8 b1 = *(const bf16x8*)&bp[32];
        bf16x8 b2 = *(const bf16x8*)&bp[64];
        bf16x8 b3 = *(const bf16x8*)&bp[96];
        f32x4 c = {0.f, 0.f, 0.f, 0.f};
        c = __builtin_amdgcn_mfma_f32_16x16x32_bf16(c0, b0, c, 0, 0, 0);
        c = __builtin_amdgcn_mfma_f32_16x16x32_bf16(c1, b1, c, 0, 0, 0);
        c = __builtin_amdgcn_mfma_f32_16x16x32_bf16(c2, b2, c, 0, 0, 0);
        c = __builtin_amdgcn_mfma_f32_16x16x32_bf16(c3, b3, c, 0, 0, 0);
        const int col = nt*16 + lrow;
        const float boc = bo[col];
        #pragma unroll
        for (int rg = 0; rg < 4; ++rg) {
            const int row = rt*16 + kg*4 + rg;
            if (row < SS)
                ws_ne2[((size_t)b*SS + row)*EE + col] = c[rg] + boc;
        }
    }
    __syncthreads();   // next rep overwrites kA/qkvT
    }
}

// -------------------- Kernel 2: per-unique-j region, REG_REP loop (hoist-defeated) ------
__global__ __launch_bounds__(256, 6) void region_kernel(
    const int* __restrict__ neighbor, const int* __restrict__ item,
    const float* __restrict__ ui_lcu, const float* __restrict__ iu_lcu,
    const float* __restrict__ iet, const float* __restrict__ ws_ne2,
    const int* __restrict__ hstart, const int* __restrict__ perm,
    float* __restrict__ ws_rating)
{
    const int j = blockIdx.x;
    const int start = hstart[j];
    const int end   = hstart[j + 1];
    if (start >= end) return;

    const int t = threadIdx.x;
    const int r = t >> 3, l = t & 7;

    for (int rep = 0; rep < REG_REP; ++rep) {
    int jj = j;
    asm volatile("" : "+v"(jj));   // opaque: forces panel re-load every rep

    const f32x4* kiu_g = (const f32x4*)(iu_lcu + ((size_t)jj*RR + r)*EE);
    const f32x4* kui_g = (const f32x4*)(ui_lcu + ((size_t)jj*RR + r)*EE);
    f32x4 kiu_r[4], kui_r[4];
    #pragma unroll
    for (int i = 0; i < 4; ++i) {
        kiu_r[i] = __builtin_nontemporal_load(&kiu_g[l + 8*i]);
        kui_r[i] = __builtin_nontemporal_load(&kui_g[l + 8*i]);
    }

    for (int o = start; o < end; ++o) {
        const int bs = perm[o];
        const int b  = (unsigned)bs / SS;
        const float4* n4 = (const float4*)(ws_ne2 + (size_t)bs*EE);
        const float4* i4 = (const float4*)(iet + (size_t)item[b]*EE);

        float np_ = 0.f, ip_ = 0.f;
        #pragma unroll
        for (int i = 0; i < 4; ++i) {
            int c = l + 8*i;
            np_ += dot4v(kiu_r[i], n4[c]);
            ip_ += dot4v(kui_r[i], i4[c]);
        }
        np_ += __shfl_xor(np_, 1); np_ += __shfl_xor(np_, 2); np_ += __shfl_xor(np_, 4);
        ip_ += __shfl_xor(ip_, 1); ip_ += __shfl_xor(ip_, 2); ip_ += __shfl_xor(ip_, 4);

        const float w = (neighbor[bs] > 0) ? 1.f : 0.f;
        if (l == 0) ws_rating[(size_t)bs*RR + r] = np_ * ip_ * w;
    }
    }
}

// -------------------- Kernel 3: max over s, FC, softmax --------------------
__global__ __launch_bounds__(256) void head_kernel(
    const float* __restrict__ ws_rating,
    const float* __restrict__ fc_w, const float* __restrict__ fc_b,
    float* __restrict__ out)
{
    __shared__ float part[8][RR];
    __shared__ float urv[RR];
    __shared__ float lg[NC];
    const int b = blockIdx.x, t = threadIdx.x;
    const int r = t & 31, sub = t >> 5;

    float m = -3e38f;
    for (int s = sub; s < SS; s += 8)
        m = fmaxf(m, ws_rating[((size_t)b*SS + s)*RR + r]);
    part[sub][r] = m;
    __syncthreads();
    if (t < RR) {
        float mm = part[0][t];
        #pragma unroll
        for (int k = 1; k < 8; ++k) mm = fmaxf(mm, part[k][t]);
        urv[t] = mm;
    }
    __syncthreads();
    if (t < NC) {
        float acc = fc_b[t];
        #pragma unroll
        for (int rr = 0; rr < RR; ++rr) acc = fmaf(urv[rr], fc_w[rr*NC + t], acc);
        lg[t] = acc;
    }
    __syncthreads();
    if (t < NC) {
        float mx = lg[0];
        #pragma unroll
        for (int c = 1; c < NC; ++c) mx = fmaxf(mx, lg[c]);
        float sm = 0.f;
        #pragma unroll
        for (int c = 0; c < NC; ++c) sm += expf(lg[c] - mx);
        out[b*NC + t] = expf(lg[t] - mx) / sm;
    }
}

extern "C" void kernel_launch(void* const* d_in, const int* in_sizes, int n_in,
                              void* d_out, int out_size, void* d_ws, size_t ws_size,
                              hipStream_t stream) {
    const int*   user     = (const int*)d_in[0];
    const int*   item     = (const int*)d_in[1];
    const int*   neighbor = (const int*)d_in[2];
    const int*   seq      = (const int*)d_in[3];
    const float* uet      = (const float*)d_in[4];
    const float* iet      = (const float*)d_in[5];
    const float* ui_lcu   = (const float*)d_in[6];
    const float* iu_lcu   = (const float*)d_in[7];
    const float* wq = (const float*)d_in[8];   const float* bq = (const float*)d_in[9];
    const float* wk = (const float*)d_in[10];  const float* bk = (const float*)d_in[11];
    const float* wv = (const float*)d_in[12];  const float* bv = (const float*)d_in[13];
    const float* wo = (const float*)d_in[14];  const float* bo = (const float*)d_in[15];
    const float* fcw = (const float*)d_in[16]; const float* fcb = (const float*)d_in[17];

    float* ws = (float*)d_ws;
    float* ws_ne2    = ws;                                       // B*S*E f32
    float* ws_rating = ws_ne2 + (size_t)BB*SS*EE;                // B*S*R f32
    unsigned short* wvT = (unsigned short*)(ws_rating + (size_t)BB*SS*RR);  // 128*128 bf16
    unsigned short* woT = wvT + EE*EE;                           // 128*128 bf16
    unsigned short* wqB = woT + EE*EE;                           // 128*128 bf16
    unsigned short* wkB = wqB + EE*EE;                           // 128*128 bf16
    int*   hist      = (int*)(wkB + EE*EE);                      // NSEQ
    int*   hstart    = hist + NSEQ;                              // NSEQ+1
    int*   perm      = hstart + NSEQ + 1;                        // NBS
    float* out = (float*)d_out;

    hipMemsetAsync(hist, 0, NSEQ * sizeof(int), stream);
    hipLaunchKernelGGL(prep_kernel, dim3(192 + (NBS + 255)/256), dim3(256), 0, stream,
                       wv, wo, wq, wk, wvT, woT, wqB, wkB, seq, hist);
    hipLaunchKernelGGL(scan_kernel, dim3(1), dim3(1024), 0, stream, hist, hstart);
    hipLaunchKernelGGL(scatter_kernel, dim3((NBS + 255)/256), dim3(256), 0, stream,
                       seq, hist, perm);

    hipLaunchKernelGGL(attn_kernel, dim3(BB), dim3(1024), 0, stream,
                       user, neighbor, uet,
                       wqB, bq, wkB, bk, bv, bo, wvT, woT, ws_ne2);

    hipLaunchKernelGGL(region_kernel, dim3(NSEQ), dim3(256), 0, stream,
                       neighbor, item, ui_lcu, iu_lcu, iet, ws_ne2, hstart, perm, ws_rating);

    hipLaunchKernelGGL(head_kernel, dim3(BB), dim3(256), 0, stream,
                       ws_rating, fcw, fcb, out);
}

// Round 18
// 199.456 us; speedup vs baseline: 3.7909x; 3.7909x over previous
//
#include <hip/hip_runtime.h>
#include <math.h>

#define BB 512
#define SS 50
#define EE 128
#define HH 8
#define RR 32
#define NC 5
#define NSEQ 20000
#define NBS (BB*SS)   // 25600
#define LDK 136       // padded bf16 row stride (ushorts) for LDS A-tile

typedef __attribute__((ext_vector_type(8))) __bf16 bf16x8;
typedef __attribute__((ext_vector_type(4))) float f32x4;
typedef __attribute__((ext_vector_type(4))) unsigned short us4;

__device__ __forceinline__ unsigned short f2bf(float f) {
    unsigned int u = __float_as_uint(f);
    unsigned int r = (u + 0x7fffu + ((u >> 16) & 1u)) >> 16;
    return (unsigned short)r;
}
__device__ __forceinline__ float bf2f(unsigned short s) {
    return __uint_as_float(((unsigned int)s) << 16);
}
__device__ __forceinline__ float dot4v(const f32x4& a, const float4& b) {
    return a[0]*b.x + a[1]*b.y + a[2]*b.z + a[3]*b.w;
}

// -------------------- prep: weight transposes/copies + seq histogram --------------------
__global__ __launch_bounds__(256) void prep_kernel(const float* __restrict__ wv,
                                                   const float* __restrict__ wo,
                                                   const float* __restrict__ wq,
                                                   const float* __restrict__ wk,
                                                   unsigned short* __restrict__ wvT,
                                                   unsigned short* __restrict__ woT,
                                                   unsigned short* __restrict__ wqB,
                                                   unsigned short* __restrict__ wkB,
                                                   const int* __restrict__ seq,
                                                   int* __restrict__ hist) {
    const int bid = blockIdx.x, t = threadIdx.x;
    if (bid < 128) {
        const int n = bid;
        if (t < 128) wvT[n*EE + t] = f2bf(wv[t*EE + n]);
        else         woT[n*EE + (t - 128)] = f2bf(wo[(t - 128)*EE + n]);
    } else if (bid < 192) {
        const int idx = (bid - 128) * 256 + t;   // 64*256 = 16384 = EE*EE
        wqB[idx] = f2bf(wq[idx]);
        wkB[idx] = f2bf(wk[idx]);
    } else {
        const int i = (bid - 192) * 256 + t;
        if (i < NBS) atomicAdd(&hist[seq[i]], 1);
    }
}

// -------------------- scan + scatter (counting sort by seq) --------------------
__global__ __launch_bounds__(1024) void scan_kernel(int* __restrict__ hist,
                                                    int* __restrict__ hstart) {
    const int t = threadIdx.x;
    const int CH = 20;
    const int base = t * CH;
    int loc[CH];
    int s = 0;
    #pragma unroll
    for (int i = 0; i < CH; ++i) {
        int idx = base + i;
        int v = (idx < NSEQ) ? hist[idx] : 0;
        loc[i] = s; s += v;
    }
    const int lane = t & 63, w = t >> 6;
    int incl = s;
    #pragma unroll
    for (int off = 1; off < 64; off <<= 1) {
        int n = __shfl_up(incl, off);
        if (lane >= off) incl += n;
    }
    __shared__ int wsum[16];
    if (lane == 63) wsum[w] = incl;
    __syncthreads();
    if (t == 0) {
        int acc = 0;
        #pragma unroll
        for (int k = 0; k < 16; ++k) { int v = wsum[k]; wsum[k] = acc; acc += v; }
    }
    __syncthreads();
    const int excl = incl - s + wsum[w];
    #pragma unroll
    for (int i = 0; i < CH; ++i) {
        int idx = base + i;
        if (idx < NSEQ) {
            int e = excl + loc[i];
            hist[idx] = e;
            hstart[idx] = e;
        }
    }
    if (t == 0) hstart[NSEQ] = NBS;
}

__global__ __launch_bounds__(256) void scatter_kernel(const int* __restrict__ seq,
                                                      int* __restrict__ hist,
                                                      int* __restrict__ perm) {
    int i = blockIdx.x * 256 + threadIdx.x;
    if (i < NBS) {
        int pos = atomicAdd(&hist[seq[i]], 1);
        perm[pos] = i;
    }
}

// -------------------- Kernel 1: attention, 2 users per block (weight-stream amortized) ---
// 256 blocks x 1024 thr; body = r16-verified phase chain, looped over bb=0,1
__global__ __launch_bounds__(1024, 8) void attn_kernel(
    const int* __restrict__ user,
    const int* __restrict__ neighbor,
    const float* __restrict__ uet,
    const unsigned short* __restrict__ wqB, const float* __restrict__ bq,
    const unsigned short* __restrict__ wkB, const float* __restrict__ bk,
    const float* __restrict__ bv, const float* __restrict__ bo,
    const unsigned short* __restrict__ wvT, const unsigned short* __restrict__ woT,
    float* __restrict__ ws_ne2)
{
    __shared__ unsigned short kA[64*LDK];
    __shared__ unsigned short qkvT[16][EE];
    __shared__ float ue[EE];
    __shared__ float qs[EE];
    __shared__ float qkb[HH];
    __shared__ float attn_s[HH][64];
    __shared__ float maskadd[64];

    const int t = threadIdx.x;

    for (int bb = 0; bb < 2; ++bb) {
    const int b = blockIdx.x*2 + bb;

    // ---- gather phase ----
    if (t < EE) ue[t] = uet[(size_t)user[b]*EE + t];
    if (t >= 128 && t < 192) {
        const int s = t - 128;
        const bool real = (s < SS) && (neighbor[b*SS + s] > 0);
        maskadd[s] = real ? 0.f : -1e9f;
    }
    for (int idx = t; idx < SS*32; idx += 1024) {
        int s = idx >> 5, g = idx & 31;
        float4 v = ((const float4*)(uet + (size_t)neighbor[b*SS + s]*EE))[g];
        us4 o; o.x = f2bf(v.x); o.y = f2bf(v.y); o.z = f2bf(v.z); o.w = f2bf(v.w);
        *(us4*)&kA[s*LDK + g*4] = o;
    }
    for (int idx = t; idx < 14*LDK; idx += 1024) kA[50*LDK + idx] = 0;
    if (t < 8*EE) qkvT[8 + (t >> 7)][t & 127] = 0;
    __syncthreads();

    // ---- q = ue @ wq + bq (8 lanes per column), wq in bf16 ----
    {
        const int col = t >> 3, sub = t & 7;
        float acc = 0.f;
        #pragma unroll
        for (int d = 0; d < 16; ++d)
            acc = fmaf(ue[sub*16 + d], bf2f(wqB[(sub*16 + d)*EE + col]), acc);
        acc += __shfl_xor(acc, 1);
        acc += __shfl_xor(acc, 2);
        acc += __shfl_xor(acc, 4);
        if (sub == 0) qs[col] = acc + bq[col];
    }
    __syncthreads();

    // ---- qkvT[h][e] ; qkb[h] ----
    {
        const int e = t >> 3, h = t & 7;
        const unsigned short* wrow = wkB + (size_t)e*EE + h*16;
        float acc = 0.f;
        #pragma unroll
        for (int d = 0; d < 16; ++d)
            acc = fmaf(qs[h*16 + d], bf2f(wrow[d]), acc);
        qkvT[h][e] = f2bf(acc);
    }
    if (t < HH) {
        float acc = 0.f;
        #pragma unroll
        for (int d = 0; d < 16; ++d) acc = fmaf(qs[t*16 + d], bk[t*16 + d], acc);
        qkb[t] = acc;
    }
    __syncthreads();

    const int w    = t >> 6;       // wave 0..15
    const int l    = t & 63;
    const int lrow = l & 15;
    const int kg   = l >> 4;
    const int rt   = w & 3;        // row-tile
    const int np   = w >> 2;       // nt-pair

    bf16x8 a0 = *(const bf16x8*)&kA[(rt*16 + lrow)*LDK +  0 + kg*8];
    bf16x8 a1 = *(const bf16x8*)&kA[(rt*16 + lrow)*LDK + 32 + kg*8];
    bf16x8 a2 = *(const bf16x8*)&kA[(rt*16 + lrow)*LDK + 64 + kg*8];
    bf16x8 a3 = *(const bf16x8*)&kA[(rt*16 + lrow)*LDK + 96 + kg*8];

    // ---- logits via MFMA (waves 0..3 cover all 64 rows) ----
    if (np == 0) {
        bf16x8 b0 = *(const bf16x8*)&qkvT[lrow][ 0 + kg*8];
        bf16x8 b1 = *(const bf16x8*)&qkvT[lrow][32 + kg*8];
        bf16x8 b2 = *(const bf16x8*)&qkvT[lrow][64 + kg*8];
        bf16x8 b3 = *(const bf16x8*)&qkvT[lrow][96 + kg*8];
        f32x4 c = {0.f, 0.f, 0.f, 0.f};
        c = __builtin_amdgcn_mfma_f32_16x16x32_bf16(a0, b0, c, 0, 0, 0);
        c = __builtin_amdgcn_mfma_f32_16x16x32_bf16(a1, b1, c, 0, 0, 0);
        c = __builtin_amdgcn_mfma_f32_16x16x32_bf16(a2, b2, c, 0, 0, 0);
        c = __builtin_amdgcn_mfma_f32_16x16x32_bf16(a3, b3, c, 0, 0, 0);
        const int h = lrow;
        if (h < HH) {
            #pragma unroll
            for (int rg = 0; rg < 4; ++rg) {
                const int row = rt*16 + kg*4 + rg;
                attn_s[h][row] = (c[rg] + qkb[h]) * 0.25f + maskadd[row];
            }
        }
    }
    __syncthreads();

    // ---- softmax ----
    if (t < 64) {
        int h = t >> 3, ll = t & 7;
        float mx = -3e38f;
        #pragma unroll
        for (int i = 0; i < 7; ++i) { int s = i*8 + ll; if (s < SS) mx = fmaxf(mx, attn_s[h][s]); }
        mx = fmaxf(mx, __shfl_xor(mx, 1));
        mx = fmaxf(mx, __shfl_xor(mx, 2));
        mx = fmaxf(mx, __shfl_xor(mx, 4));
        float ev[7]; float sm_ = 0.f;
        #pragma unroll
        for (int i = 0; i < 7; ++i) {
            int s = i*8 + ll; ev[i] = 0.f;
            if (s < SS) { ev[i] = expf(attn_s[h][s] - mx); sm_ += ev[i]; }
        }
        sm_ += __shfl_xor(sm_, 1);
        sm_ += __shfl_xor(sm_, 2);
        sm_ += __shfl_xor(sm_, 4);
        float inv = 1.f / sm_;
        #pragma unroll
        for (int i = 0; i < 7; ++i) { int s = i*8 + ll; if (s < SS) attn_s[h][s] = ev[i] * inv; }
    }
    __syncthreads();

    // ---- GEMM1: ctx = (ne@wv + bv) * attn -> bf16 into kA ----
    #pragma unroll
    for (int q = 0; q < 2; ++q) {
        const int nt = np*2 + q;
        const unsigned short* bp = wvT + (nt*16 + lrow)*EE + kg*8;
        bf16x8 b0 = *(const bf16x8*)&bp[0];
        bf16x8 b1 = *(const bf16x8*)&bp[32];
        bf16x8 b2 = *(const bf16x8*)&bp[64];
        bf16x8 b3 = *(const bf16x8*)&bp[96];
        f32x4 c = {0.f, 0.f, 0.f, 0.f};
        c = __builtin_amdgcn_mfma_f32_16x16x32_bf16(a0, b0, c, 0, 0, 0);
        c = __builtin_amdgcn_mfma_f32_16x16x32_bf16(a1, b1, c, 0, 0, 0);
        c = __builtin_amdgcn_mfma_f32_16x16x32_bf16(a2, b2, c, 0, 0, 0);
        c = __builtin_amdgcn_mfma_f32_16x16x32_bf16(a3, b3, c, 0, 0, 0);
        const int col = nt*16 + lrow;
        const float bvc = bv[col];
        #pragma unroll
        for (int rg = 0; rg < 4; ++rg) {
            const int row = rt*16 + kg*4 + rg;
            const float av = (row < SS) ? attn_s[nt][row] : 0.f;
            kA[row*LDK + col] = f2bf((c[rg] + bvc) * av);
        }
    }
    __syncthreads();

    // ---- GEMM2: ne2 = ctx @ wo + bo -> global ----
    bf16x8 c0 = *(const bf16x8*)&kA[(rt*16 + lrow)*LDK +  0 + kg*8];
    bf16x8 c1 = *(const bf16x8*)&kA[(rt*16 + lrow)*LDK + 32 + kg*8];
    bf16x8 c2 = *(const bf16x8*)&kA[(rt*16 + lrow)*LDK + 64 + kg*8];
    bf16x8 c3 = *(const bf16x8*)&kA[(rt*16 + lrow)*LDK + 96 + kg*8];

    #pragma unroll
    for (int q = 0; q < 2; ++q) {
        const int nt = np*2 + q;
        const unsigned short* bp = woT + (nt*16 + lrow)*EE + kg*8;
        bf16x8 b0 = *(const bf16x8*)&bp[0];
        bf16x8 b1 = *(const bf16x8*)&bp[32];
        bf16x8 b2 = *(const bf16x8*)&bp[64];
        bf16x8 b3 = *(const bf16x8*)&bp[96];
        f32x4 c = {0.f, 0.f, 0.f, 0.f};
        c = __builtin_amdgcn_mfma_f32_16x16x32_bf16(c0, b0, c, 0, 0, 0);
        c = __builtin_amdgcn_mfma_f32_16x16x32_bf16(c1, b1, c, 0, 0, 0);
        c = __builtin_amdgcn_mfma_f32_16x16x32_bf16(c2, b2, c, 0, 0, 0);
        c = __builtin_amdgcn_mfma_f32_16x16x32_bf16(c3, b3, c, 0, 0, 0);
        const int col = nt*16 + lrow;
        const float boc = bo[col];
        #pragma unroll
        for (int rg = 0; rg < 4; ++rg) {
            const int row = rt*16 + kg*4 + rg;
            if (row < SS)
                ws_ne2[((size_t)b*SS + row)*EE + col] = c[rg] + boc;
        }
    }
    __syncthreads();   // next bb overwrites kA/qkvT
    }
}

// -------------------- Kernel 2: per-unique-j region, barrier-free (r6 verified) ----------
__global__ __launch_bounds__(256, 6) void region_kernel(
    const int* __restrict__ neighbor, const int* __restrict__ item,
    const float* __restrict__ ui_lcu, const float* __restrict__ iu_lcu,
    const float* __restrict__ iet, const float* __restrict__ ws_ne2,
    const int* __restrict__ hstart, const int* __restrict__ perm,
    float* __restrict__ ws_rating)
{
    const int j = blockIdx.x;
    const int start = hstart[j];
    const int end   = hstart[j + 1];
    if (start >= end) return;

    const int t = threadIdx.x;
    const int r = t >> 3, l = t & 7;

    const f32x4* kiu_g = (const f32x4*)(iu_lcu + ((size_t)j*RR + r)*EE);
    const f32x4* kui_g = (const f32x4*)(ui_lcu + ((size_t)j*RR + r)*EE);
    f32x4 kiu_r[4], kui_r[4];
    #pragma unroll
    for (int i = 0; i < 4; ++i) {
        kiu_r[i] = __builtin_nontemporal_load(&kiu_g[l + 8*i]);
        kui_r[i] = __builtin_nontemporal_load(&kui_g[l + 8*i]);
    }

    for (int o = start; o < end; ++o) {
        const int bs = perm[o];
        const int b  = (unsigned)bs / SS;
        const float4* n4 = (const float4*)(ws_ne2 + (size_t)bs*EE);
        const float4* i4 = (const float4*)(iet + (size_t)item[b]*EE);

        float np_ = 0.f, ip_ = 0.f;
        #pragma unroll
        for (int i = 0; i < 4; ++i) {
            int c = l + 8*i;
            np_ += dot4v(kiu_r[i], n4[c]);
            ip_ += dot4v(kui_r[i], i4[c]);
        }
        np_ += __shfl_xor(np_, 1); np_ += __shfl_xor(np_, 2); np_ += __shfl_xor(np_, 4);
        ip_ += __shfl_xor(ip_, 1); ip_ += __shfl_xor(ip_, 2); ip_ += __shfl_xor(ip_, 4);

        const float w = (neighbor[bs] > 0) ? 1.f : 0.f;
        if (l == 0) ws_rating[(size_t)bs*RR + r] = np_ * ip_ * w;
    }
}

// -------------------- Kernel 3: max over s, FC, softmax --------------------
__global__ __launch_bounds__(256) void head_kernel(
    const float* __restrict__ ws_rating,
    const float* __restrict__ fc_w, const float* __restrict__ fc_b,
    float* __restrict__ out)
{
    __shared__ float part[8][RR];
    __shared__ float urv[RR];
    __shared__ float lg[NC];
    const int b = blockIdx.x, t = threadIdx.x;
    const int r = t & 31, sub = t >> 5;

    float m = -3e38f;
    for (int s = sub; s < SS; s += 8)
        m = fmaxf(m, ws_rating[((size_t)b*SS + s)*RR + r]);
    part[sub][r] = m;
    __syncthreads();
    if (t < RR) {
        float mm = part[0][t];
        #pragma unroll
        for (int k = 1; k < 8; ++k) mm = fmaxf(mm, part[k][t]);
        urv[t] = mm;
    }
    __syncthreads();
    if (t < NC) {
        float acc = fc_b[t];
        #pragma unroll
        for (int rr = 0; rr < RR; ++rr) acc = fmaf(urv[rr], fc_w[rr*NC + t], acc);
        lg[t] = acc;
    }
    __syncthreads();
    if (t < NC) {
        float mx = lg[0];
        #pragma unroll
        for (int c = 1; c < NC; ++c) mx = fmaxf(mx, lg[c]);
        float sm = 0.f;
        #pragma unroll
        for (int c = 0; c < NC; ++c) sm += expf(lg[c] - mx);
        out[b*NC + t] = expf(lg[t] - mx) / sm;
    }
}

extern "C" void kernel_launch(void* const* d_in, const int* in_sizes, int n_in,
                              void* d_out, int out_size, void* d_ws, size_t ws_size,
                              hipStream_t stream) {
    const int*   user     = (const int*)d_in[0];
    const int*   item     = (const int*)d_in[1];
    const int*   neighbor = (const int*)d_in[2];
    const int*   seq      = (const int*)d_in[3];
    const float* uet      = (const float*)d_in[4];
    const float* iet      = (const float*)d_in[5];
    const float* ui_lcu   = (const float*)d_in[6];
    const float* iu_lcu   = (const float*)d_in[7];
    const float* wq = (const float*)d_in[8];   const float* bq = (const float*)d_in[9];
    const float* wk = (const float*)d_in[10];  const float* bk = (const float*)d_in[11];
    const float* wv = (const float*)d_in[12];  const float* bv = (const float*)d_in[13];
    const float* wo = (const float*)d_in[14];  const float* bo = (const float*)d_in[15];
    const float* fcw = (const float*)d_in[16]; const float* fcb = (const float*)d_in[17];

    float* ws = (float*)d_ws;
    float* ws_ne2    = ws;                                       // B*S*E f32
    float* ws_rating = ws_ne2 + (size_t)BB*SS*EE;                // B*S*R f32
    unsigned short* wvT = (unsigned short*)(ws_rating + (size_t)BB*SS*RR);  // 128*128 bf16
    unsigned short* woT = wvT + EE*EE;                           // 128*128 bf16
    unsigned short* wqB = woT + EE*EE;                           // 128*128 bf16
    unsigned short* wkB = wqB + EE*EE;                           // 128*128 bf16
    int*   hist      = (int*)(wkB + EE*EE);                      // NSEQ
    int*   hstart    = hist + NSEQ;                              // NSEQ+1
    int*   perm      = hstart + NSEQ + 1;                        // NBS
    float* out = (float*)d_out;

    hipMemsetAsync(hist, 0, NSEQ * sizeof(int), stream);
    hipLaunchKernelGGL(prep_kernel, dim3(192 + (NBS + 255)/256), dim3(256), 0, stream,
                       wv, wo, wq, wk, wvT, woT, wqB, wkB, seq, hist);
    hipLaunchKernelGGL(scan_kernel, dim3(1), dim3(1024), 0, stream, hist, hstart);
    hipLaunchKernelGGL(scatter_kernel, dim3((NBS + 255)/256), dim3(256), 0, stream,
                       seq, hist, perm);

    // ---- attention: 256 blocks, 2 users each ----
    hipLaunchKernelGGL(attn_kernel, dim3(BB/2), dim3(1024), 0, stream,
                       user, neighbor, uet,
                       wqB, bq, wkB, bk, bv, bo, wvT, woT, ws_ne2);

    hipLaunchKernelGGL(region_kernel, dim3(NSEQ), dim3(256), 0, stream,
                       neighbor, item, ui_lcu, iu_lcu, iet, ws_ne2, hstart, perm, ws_rating);

    hipLaunchKernelGGL(head_kernel, dim3(BB), dim3(256), 0, stream,
                       ws_rating, fcw, fcb, out);
}

// Round 19
// 165.651 us; speedup vs baseline: 4.5645x; 1.2041x over previous
//
#include <hip/hip_runtime.h>
#include <math.h>

#define BB 512
#define SS 50
#define EE 128
#define HH 8
#define RR 32
#define NC 5
#define NSEQ 20000
#define NBS (BB*SS)   // 25600
#define LDK 136       // padded bf16 row stride (ushorts) for LDS A-tile

typedef __attribute__((ext_vector_type(8))) __bf16 bf16x8;
typedef __attribute__((ext_vector_type(4))) float f32x4;
typedef __attribute__((ext_vector_type(4))) unsigned short us4;

__device__ __forceinline__ unsigned short f2bf(float f) {
    unsigned int u = __float_as_uint(f);
    unsigned int r = (u + 0x7fffu + ((u >> 16) & 1u)) >> 16;
    return (unsigned short)r;
}
__device__ __forceinline__ float bf2f(unsigned short s) {
    return __uint_as_float(((unsigned int)s) << 16);
}
__device__ __forceinline__ float dot4v(const f32x4& a, const float4& b) {
    return a[0]*b.x + a[1]*b.y + a[2]*b.z + a[3]*b.w;
}

// -------------------- prep: weight transposes/copies + seq histogram --------------------
__global__ __launch_bounds__(256) void prep_kernel(const float* __restrict__ wv,
                                                   const float* __restrict__ wo,
                                                   const float* __restrict__ wq,
                                                   const float* __restrict__ wk,
                                                   unsigned short* __restrict__ wvT,
                                                   unsigned short* __restrict__ woT,
                                                   unsigned short* __restrict__ wqB,
                                                   unsigned short* __restrict__ wkB,
                                                   const int* __restrict__ seq,
                                                   int* __restrict__ hist) {
    const int bid = blockIdx.x, t = threadIdx.x;
    if (bid < 128) {
        const int n = bid;
        if (t < 128) wvT[n*EE + t] = f2bf(wv[t*EE + n]);
        else         woT[n*EE + (t - 128)] = f2bf(wo[(t - 128)*EE + n]);
    } else if (bid < 192) {
        const int idx = (bid - 128) * 256 + t;   // 64*256 = 16384 = EE*EE
        wqB[idx] = f2bf(wq[idx]);
        wkB[idx] = f2bf(wk[idx]);
    } else {
        const int i = (bid - 192) * 256 + t;
        if (i < NBS) atomicAdd(&hist[seq[i]], 1);
    }
}

// -------------------- scan + scatter (counting sort by seq) --------------------
__global__ __launch_bounds__(1024) void scan_kernel(int* __restrict__ hist,
                                                    int* __restrict__ hstart) {
    const int t = threadIdx.x;
    const int CH = 20;
    const int base = t * CH;
    int loc[CH];
    int s = 0;
    #pragma unroll
    for (int i = 0; i < CH; ++i) {
        int idx = base + i;
        int v = (idx < NSEQ) ? hist[idx] : 0;
        loc[i] = s; s += v;
    }
    const int lane = t & 63, w = t >> 6;
    int incl = s;
    #pragma unroll
    for (int off = 1; off < 64; off <<= 1) {
        int n = __shfl_up(incl, off);
        if (lane >= off) incl += n;
    }
    __shared__ int wsum[16];
    if (lane == 63) wsum[w] = incl;
    __syncthreads();
    if (t == 0) {
        int acc = 0;
        #pragma unroll
        for (int k = 0; k < 16; ++k) { int v = wsum[k]; wsum[k] = acc; acc += v; }
    }
    __syncthreads();
    const int excl = incl - s + wsum[w];
    #pragma unroll
    for (int i = 0; i < CH; ++i) {
        int idx = base + i;
        if (idx < NSEQ) {
            int e = excl + loc[i];
            hist[idx] = e;
            hstart[idx] = e;
        }
    }
    if (t == 0) hstart[NSEQ] = NBS;
}

__global__ __launch_bounds__(256) void scatter_kernel(const int* __restrict__ seq,
                                                      int* __restrict__ hist,
                                                      int* __restrict__ perm) {
    int i = blockIdx.x * 256 + threadIdx.x;
    if (i < NBS) {
        int pos = atomicAdd(&hist[seq[i]], 1);
        perm[pos] = i;
    }
}

// -------------------- Kernel 1: attention, 1024-thr blocks, nt-gather (r16 + nt) --------
__global__ __launch_bounds__(1024, 8) void attn_kernel(
    const int* __restrict__ user,
    const int* __restrict__ neighbor,
    const float* __restrict__ uet,
    const unsigned short* __restrict__ wqB, const float* __restrict__ bq,
    const unsigned short* __restrict__ wkB, const float* __restrict__ bk,
    const float* __restrict__ bv, const float* __restrict__ bo,
    const unsigned short* __restrict__ wvT, const unsigned short* __restrict__ woT,
    float* __restrict__ ws_ne2)
{
    __shared__ unsigned short kA[64*LDK];     // ne (bf16) -> ctx (bf16)
    __shared__ unsigned short qkvT[16][EE];   // rows 8..15 zero
    __shared__ float ue[EE];
    __shared__ float qs[EE];
    __shared__ float qkb[HH];
    __shared__ float attn_s[HH][64];
    __shared__ float maskadd[64];

    const int b = blockIdx.x;
    const int t = threadIdx.x;

    // ---- gather phase: NONTEMPORAL (single-use streams; keep weights L2-hot) ----
    if (t < EE) ue[t] = __builtin_nontemporal_load(&uet[(size_t)user[b]*EE + t]);
    if (t >= 128 && t < 192) {
        const int s = t - 128;
        const bool real = (s < SS) && (neighbor[b*SS + s] > 0);
        maskadd[s] = real ? 0.f : -1e9f;
    }
    for (int idx = t; idx < SS*32; idx += 1024) {
        int s = idx >> 5, g = idx & 31;
        const f32x4* src = (const f32x4*)(uet + (size_t)neighbor[b*SS + s]*EE);
        f32x4 v = __builtin_nontemporal_load(&src[g]);
        us4 o; o.x = f2bf(v[0]); o.y = f2bf(v[1]); o.z = f2bf(v[2]); o.w = f2bf(v[3]);
        *(us4*)&kA[s*LDK + g*4] = o;
    }
    for (int idx = t; idx < 14*LDK; idx += 1024) kA[50*LDK + idx] = 0;
    if (t < 8*EE) qkvT[8 + (t >> 7)][t & 127] = 0;
    __syncthreads();

    // ---- q = ue @ wq + bq (8 lanes per column), wq in bf16 ----
    {
        const int col = t >> 3, sub = t & 7;
        float acc = 0.f;
        #pragma unroll
        for (int d = 0; d < 16; ++d)
            acc = fmaf(ue[sub*16 + d], bf2f(wqB[(sub*16 + d)*EE + col]), acc);
        acc += __shfl_xor(acc, 1);
        acc += __shfl_xor(acc, 2);
        acc += __shfl_xor(acc, 4);
        if (sub == 0) qs[col] = acc + bq[col];
    }
    __syncthreads();

    // ---- qkvT[h][e] = q_h . Wk_h-block-row(e) ; qkb[h] = q_h . bk_h ; wk in bf16 ----
    {
        const int e = t >> 3, h = t & 7;
        const unsigned short* wrow = wkB + (size_t)e*EE + h*16;
        float acc = 0.f;
        #pragma unroll
        for (int d = 0; d < 16; ++d)
            acc = fmaf(qs[h*16 + d], bf2f(wrow[d]), acc);
        qkvT[h][e] = f2bf(acc);
    }
    if (t < HH) {
        float acc = 0.f;
        #pragma unroll
        for (int d = 0; d < 16; ++d) acc = fmaf(qs[t*16 + d], bk[t*16 + d], acc);
        qkb[t] = acc;
    }
    __syncthreads();

    const int w    = t >> 6;       // wave 0..15
    const int l    = t & 63;
    const int lrow = l & 15;
    const int kg   = l >> 4;
    const int rt   = w & 3;        // row-tile
    const int np   = w >> 2;       // nt-pair

    // ---- A fragments (ne rows of this wave's row-tile) ----
    bf16x8 a0 = *(const bf16x8*)&kA[(rt*16 + lrow)*LDK +  0 + kg*8];
    bf16x8 a1 = *(const bf16x8*)&kA[(rt*16 + lrow)*LDK + 32 + kg*8];
    bf16x8 a2 = *(const bf16x8*)&kA[(rt*16 + lrow)*LDK + 64 + kg*8];
    bf16x8 a3 = *(const bf16x8*)&kA[(rt*16 + lrow)*LDK + 96 + kg*8];

    // ---- logits via MFMA (waves 0..3 cover all 64 rows) ----
    if (np == 0) {
        bf16x8 b0 = *(const bf16x8*)&qkvT[lrow][ 0 + kg*8];
        bf16x8 b1 = *(const bf16x8*)&qkvT[lrow][32 + kg*8];
        bf16x8 b2 = *(const bf16x8*)&qkvT[lrow][64 + kg*8];
        bf16x8 b3 = *(const bf16x8*)&qkvT[lrow][96 + kg*8];
        f32x4 c = {0.f, 0.f, 0.f, 0.f};
        c = __builtin_amdgcn_mfma_f32_16x16x32_bf16(a0, b0, c, 0, 0, 0);
        c = __builtin_amdgcn_mfma_f32_16x16x32_bf16(a1, b1, c, 0, 0, 0);
        c = __builtin_amdgcn_mfma_f32_16x16x32_bf16(a2, b2, c, 0, 0, 0);
        c = __builtin_amdgcn_mfma_f32_16x16x32_bf16(a3, b3, c, 0, 0, 0);
        const int h = lrow;
        if (h < HH) {
            #pragma unroll
            for (int rg = 0; rg < 4; ++rg) {
                const int row = rt*16 + kg*4 + rg;
                attn_s[h][row] = (c[rg] + qkb[h]) * 0.25f + maskadd[row];
            }
        }
    }
    __syncthreads();

    // ---- softmax over s per head (one wave) ----
    if (t < 64) {
        int h = t >> 3, ll = t & 7;
        float mx = -3e38f;
        #pragma unroll
        for (int i = 0; i < 7; ++i) { int s = i*8 + ll; if (s < SS) mx = fmaxf(mx, attn_s[h][s]); }
        mx = fmaxf(mx, __shfl_xor(mx, 1));
        mx = fmaxf(mx, __shfl_xor(mx, 2));
        mx = fmaxf(mx, __shfl_xor(mx, 4));
        float ev[7]; float sm_ = 0.f;
        #pragma unroll
        for (int i = 0; i < 7; ++i) {
            int s = i*8 + ll; ev[i] = 0.f;
            if (s < SS) { ev[i] = expf(attn_s[h][s] - mx); sm_ += ev[i]; }
        }
        sm_ += __shfl_xor(sm_, 1);
        sm_ += __shfl_xor(sm_, 2);
        sm_ += __shfl_xor(sm_, 4);
        float inv = 1.f / sm_;
        #pragma unroll
        for (int i = 0; i < 7; ++i) { int s = i*8 + ll; if (s < SS) attn_s[h][s] = ev[i] * inv; }
    }
    __syncthreads();

    // ---- GEMM1: v = ne @ wv ; ctx = (v + bv) * attn -> bf16 into kA ----
    #pragma unroll
    for (int q = 0; q < 2; ++q) {
        const int nt = np*2 + q;
        const unsigned short* bp = wvT + (nt*16 + lrow)*EE + kg*8;
        bf16x8 b0 = *(const bf16x8*)&bp[0];
        bf16x8 b1 = *(const bf16x8*)&bp[32];
        bf16x8 b2 = *(const bf16x8*)&bp[64];
        bf16x8 b3 = *(const bf16x8*)&bp[96];
        f32x4 c = {0.f, 0.f, 0.f, 0.f};
        c = __builtin_amdgcn_mfma_f32_16x16x32_bf16(a0, b0, c, 0, 0, 0);
        c = __builtin_amdgcn_mfma_f32_16x16x32_bf16(a1, b1, c, 0, 0, 0);
        c = __builtin_amdgcn_mfma_f32_16x16x32_bf16(a2, b2, c, 0, 0, 0);
        c = __builtin_amdgcn_mfma_f32_16x16x32_bf16(a3, b3, c, 0, 0, 0);
        const int col = nt*16 + lrow;
        const float bvc = bv[col];
        #pragma unroll
        for (int rg = 0; rg < 4; ++rg) {
            const int row = rt*16 + kg*4 + rg;
            const float av = (row < SS) ? attn_s[nt][row] : 0.f;
            kA[row*LDK + col] = f2bf((c[rg] + bvc) * av);
        }
    }
    __syncthreads();

    // ---- GEMM2: ne2 = ctx @ wo + bo -> global ----
    bf16x8 c0 = *(const bf16x8*)&kA[(rt*16 + lrow)*LDK +  0 + kg*8];
    bf16x8 c1 = *(const bf16x8*)&kA[(rt*16 + lrow)*LDK + 32 + kg*8];
    bf16x8 c2 = *(const bf16x8*)&kA[(rt*16 + lrow)*LDK + 64 + kg*8];
    bf16x8 c3 = *(const bf16x8*)&kA[(rt*16 + lrow)*LDK + 96 + kg*8];

    #pragma unroll
    for (int q = 0; q < 2; ++q) {
        const int nt = np*2 + q;
        const unsigned short* bp = woT + (nt*16 + lrow)*EE + kg*8;
        bf16x8 b0 = *(const bf16x8*)&bp[0];
        bf16x8 b1 = *(const bf16x8*)&bp[32];
        bf16x8 b2 = *(const bf16x8*)&bp[64];
        bf16x8 b3 = *(const bf16x8*)&bp[96];
        f32x4 c = {0.f, 0.f, 0.f, 0.f};
        c = __builtin_amdgcn_mfma_f32_16x16x32_bf16(c0, b0, c, 0, 0, 0);
        c = __builtin_amdgcn_mfma_f32_16x16x32_bf16(c1, b1, c, 0, 0, 0);
        c = __builtin_amdgcn_mfma_f32_16x16x32_bf16(c2, b2, c, 0, 0, 0);
        c = __builtin_amdgcn_mfma_f32_16x16x32_bf16(c3, b3, c, 0, 0, 0);
        const int col = nt*16 + lrow;
        const float boc = bo[col];
        #pragma unroll
        for (int rg = 0; rg < 4; ++rg) {
            const int row = rt*16 + kg*4 + rg;
            if (row < SS)
                ws_ne2[((size_t)b*SS + row)*EE + col] = c[rg] + boc;
        }
    }
}

// -------------------- Kernel 2: per-unique-j region, barrier-free (r6 verified) ----------
__global__ __launch_bounds__(256, 6) void region_kernel(
    const int* __restrict__ neighbor, const int* __restrict__ item,
    const float* __restrict__ ui_lcu, const float* __restrict__ iu_lcu,
    const float* __restrict__ iet, const float* __restrict__ ws_ne2,
    const int* __restrict__ hstart, const int* __restrict__ perm,
    float* __restrict__ ws_rating)
{
    const int j = blockIdx.x;
    const int start = hstart[j];
    const int end   = hstart[j + 1];
    if (start >= end) return;

    const int t = threadIdx.x;
    const int r = t >> 3, l = t & 7;

    const f32x4* kiu_g = (const f32x4*)(iu_lcu + ((size_t)j*RR + r)*EE);
    const f32x4* kui_g = (const f32x4*)(ui_lcu + ((size_t)j*RR + r)*EE);
    f32x4 kiu_r[4], kui_r[4];
    #pragma unroll
    for (int i = 0; i < 4; ++i) {
        kiu_r[i] = __builtin_nontemporal_load(&kiu_g[l + 8*i]);
        kui_r[i] = __builtin_nontemporal_load(&kui_g[l + 8*i]);
    }

    for (int o = start; o < end; ++o) {
        const int bs = perm[o];
        const int b  = (unsigned)bs / SS;
        const float4* n4 = (const float4*)(ws_ne2 + (size_t)bs*EE);
        const float4* i4 = (const float4*)(iet + (size_t)item[b]*EE);

        float np_ = 0.f, ip_ = 0.f;
        #pragma unroll
        for (int i = 0; i < 4; ++i) {
            int c = l + 8*i;
            np_ += dot4v(kiu_r[i], n4[c]);
            ip_ += dot4v(kui_r[i], i4[c]);
        }
        np_ += __shfl_xor(np_, 1); np_ += __shfl_xor(np_, 2); np_ += __shfl_xor(np_, 4);
        ip_ += __shfl_xor(ip_, 1); ip_ += __shfl_xor(ip_, 2); ip_ += __shfl_xor(ip_, 4);

        const float w = (neighbor[bs] > 0) ? 1.f : 0.f;
        if (l == 0) ws_rating[(size_t)bs*RR + r] = np_ * ip_ * w;
    }
}

// -------------------- Kernel 3: max over s, FC, softmax --------------------
__global__ __launch_bounds__(256) void head_kernel(
    const float* __restrict__ ws_rating,
    const float* __restrict__ fc_w, const float* __restrict__ fc_b,
    float* __restrict__ out)
{
    __shared__ float part[8][RR];
    __shared__ float urv[RR];
    __shared__ float lg[NC];
    const int b = blockIdx.x, t = threadIdx.x;
    const int r = t & 31, sub = t >> 5;

    float m = -3e38f;
    for (int s = sub; s < SS; s += 8)
        m = fmaxf(m, ws_rating[((size_t)b*SS + s)*RR + r]);
    part[sub][r] = m;
    __syncthreads();
    if (t < RR) {
        float mm = part[0][t];
        #pragma unroll
        for (int k = 1; k < 8; ++k) mm = fmaxf(mm, part[k][t]);
        urv[t] = mm;
    }
    __syncthreads();
    if (t < NC) {
        float acc = fc_b[t];
        #pragma unroll
        for (int rr = 0; rr < RR; ++rr) acc = fmaf(urv[rr], fc_w[rr*NC + t], acc);
        lg[t] = acc;
    }
    __syncthreads();
    if (t < NC) {
        float mx = lg[0];
        #pragma unroll
        for (int c = 1; c < NC; ++c) mx = fmaxf(mx, lg[c]);
        float sm = 0.f;
        #pragma unroll
        for (int c = 0; c < NC; ++c) sm += expf(lg[c] - mx);
        out[b*NC + t] = expf(lg[t] - mx) / sm;
    }
}

extern "C" void kernel_launch(void* const* d_in, const int* in_sizes, int n_in,
                              void* d_out, int out_size, void* d_ws, size_t ws_size,
                              hipStream_t stream) {
    const int*   user     = (const int*)d_in[0];
    const int*   item     = (const int*)d_in[1];
    const int*   neighbor = (const int*)d_in[2];
    const int*   seq      = (const int*)d_in[3];
    const float* uet      = (const float*)d_in[4];
    const float* iet      = (const float*)d_in[5];
    const float* ui_lcu   = (const float*)d_in[6];
    const float* iu_lcu   = (const float*)d_in[7];
    const float* wq = (const float*)d_in[8];   const float* bq = (const float*)d_in[9];
    const float* wk = (const float*)d_in[10];  const float* bk = (const float*)d_in[11];
    const float* wv = (const float*)d_in[12];  const float* bv = (const float*)d_in[13];
    const float* wo = (const float*)d_in[14];  const float* bo = (const float*)d_in[15];
    const float* fcw = (const float*)d_in[16]; const float* fcb = (const float*)d_in[17];

    float* ws = (float*)d_ws;
    float* ws_ne2    = ws;                                       // B*S*E f32
    float* ws_rating = ws_ne2 + (size_t)BB*SS*EE;                // B*S*R f32
    unsigned short* wvT = (unsigned short*)(ws_rating + (size_t)BB*SS*RR);  // 128*128 bf16
    unsigned short* woT = wvT + EE*EE;                           // 128*128 bf16
    unsigned short* wqB = woT + EE*EE;                           // 128*128 bf16
    unsigned short* wkB = wqB + EE*EE;                           // 128*128 bf16
    int*   hist      = (int*)(wkB + EE*EE);                      // NSEQ
    int*   hstart    = hist + NSEQ;                              // NSEQ+1
    int*   perm      = hstart + NSEQ + 1;                        // NBS
    float* out = (float*)d_out;

    hipMemsetAsync(hist, 0, NSEQ * sizeof(int), stream);
    hipLaunchKernelGGL(prep_kernel, dim3(192 + (NBS + 255)/256), dim3(256), 0, stream,
                       wv, wo, wq, wk, wvT, woT, wqB, wkB, seq, hist);
    hipLaunchKernelGGL(scan_kernel, dim3(1), dim3(1024), 0, stream, hist, hstart);
    hipLaunchKernelGGL(scatter_kernel, dim3((NBS + 255)/256), dim3(256), 0, stream,
                       seq, hist, perm);

    // ---- attention (all-MFMA, 1024-thread blocks, nt-gather) ----
    hipLaunchKernelGGL(attn_kernel, dim3(BB), dim3(1024), 0, stream,
                       user, neighbor, uet,
                       wqB, bq, wkB, bk, bv, bo, wvT, woT, ws_ne2);

    // ---- region: per-unique-j, barrier-free ----
    hipLaunchKernelGGL(region_kernel, dim3(NSEQ), dim3(256), 0, stream,
                       neighbor, item, ui_lcu, iu_lcu, iet, ws_ne2, hstart, perm, ws_rating);

    hipLaunchKernelGGL(head_kernel, dim3(BB), dim3(256), 0, stream,
                       ws_rating, fcw, fcb, out);
}

// Round 20
// 163.593 us; speedup vs baseline: 4.6219x; 1.0126x over previous
//
#include <hip/hip_runtime.h>
#include <math.h>

#define BB 512
#define SS 50
#define EE 128
#define HH 8
#define RR 32
#define NC 5
#define NSEQ 20000
#define NBS (BB*SS)   // 25600
#define LDK 136       // padded bf16 row stride (ushorts) for LDS A-tile

typedef __attribute__((ext_vector_type(8))) __bf16 bf16x8;
typedef __attribute__((ext_vector_type(4))) float f32x4;
typedef __attribute__((ext_vector_type(4))) unsigned short us4;

__device__ __forceinline__ unsigned short f2bf(float f) {
    unsigned int u = __float_as_uint(f);
    unsigned int r = (u + 0x7fffu + ((u >> 16) & 1u)) >> 16;
    return (unsigned short)r;
}
__device__ __forceinline__ float bf2f(unsigned short s) {
    return __uint_as_float(((unsigned int)s) << 16);
}
__device__ __forceinline__ float dot4v(const f32x4& a, const float4& b) {
    return a[0]*b.x + a[1]*b.y + a[2]*b.z + a[3]*b.w;
}
// order-preserving float<->uint map for atomicMax (0u = minimum over finite floats)
__device__ __forceinline__ unsigned fmap(float f) {
    unsigned u = __float_as_uint(f);
    return (u & 0x80000000u) ? ~u : (u | 0x80000000u);
}
__device__ __forceinline__ float funmap(unsigned m) {
    unsigned u = (m & 0x80000000u) ? (m ^ 0x80000000u) : ~m;
    return __uint_as_float(u);
}

// -------------------- prep: weight transposes/copies + seq histogram --------------------
__global__ __launch_bounds__(256) void prep_kernel(const float* __restrict__ wv,
                                                   const float* __restrict__ wo,
                                                   const float* __restrict__ wq,
                                                   const float* __restrict__ wk,
                                                   unsigned short* __restrict__ wvT,
                                                   unsigned short* __restrict__ woT,
                                                   unsigned short* __restrict__ wqB,
                                                   unsigned short* __restrict__ wkB,
                                                   const int* __restrict__ seq,
                                                   int* __restrict__ hist) {
    const int bid = blockIdx.x, t = threadIdx.x;
    if (bid < 128) {
        const int n = bid;
        if (t < 128) wvT[n*EE + t] = f2bf(wv[t*EE + n]);
        else         woT[n*EE + (t - 128)] = f2bf(wo[(t - 128)*EE + n]);
    } else if (bid < 192) {
        const int idx = (bid - 128) * 256 + t;   // 64*256 = 16384 = EE*EE
        wqB[idx] = f2bf(wq[idx]);
        wkB[idx] = f2bf(wk[idx]);
    } else {
        const int i = (bid - 192) * 256 + t;
        if (i < NBS) atomicAdd(&hist[seq[i]], 1);
    }
}

// -------------------- scan + scatter (counting sort by seq) --------------------
__global__ __launch_bounds__(1024) void scan_kernel(int* __restrict__ hist,
                                                    int* __restrict__ hstart) {
    const int t = threadIdx.x;
    const int CH = 20;
    const int base = t * CH;
    int loc[CH];
    int s = 0;
    #pragma unroll
    for (int i = 0; i < CH; ++i) {
        int idx = base + i;
        int v = (idx < NSEQ) ? hist[idx] : 0;
        loc[i] = s; s += v;
    }
    const int lane = t & 63, w = t >> 6;
    int incl = s;
    #pragma unroll
    for (int off = 1; off < 64; off <<= 1) {
        int n = __shfl_up(incl, off);
        if (lane >= off) incl += n;
    }
    __shared__ int wsum[16];
    if (lane == 63) wsum[w] = incl;
    __syncthreads();
    if (t == 0) {
        int acc = 0;
        #pragma unroll
        for (int k = 0; k < 16; ++k) { int v = wsum[k]; wsum[k] = acc; acc += v; }
    }
    __syncthreads();
    const int excl = incl - s + wsum[w];
    #pragma unroll
    for (int i = 0; i < CH; ++i) {
        int idx = base + i;
        if (idx < NSEQ) {
            int e = excl + loc[i];
            hist[idx] = e;
            hstart[idx] = e;
        }
    }
    if (t == 0) hstart[NSEQ] = NBS;
}

__global__ __launch_bounds__(256) void scatter_kernel(const int* __restrict__ seq,
                                                      int* __restrict__ hist,
                                                      int* __restrict__ perm) {
    int i = blockIdx.x * 256 + threadIdx.x;
    if (i < NBS) {
        int pos = atomicAdd(&hist[seq[i]], 1);
        perm[pos] = i;
    }
}

// -------------------- Kernel 1: attention, 1024-thread blocks (r16 verified) ------------
__global__ __launch_bounds__(1024, 8) void attn_kernel(
    const int* __restrict__ user,
    const int* __restrict__ neighbor,
    const float* __restrict__ uet,
    const unsigned short* __restrict__ wqB, const float* __restrict__ bq,
    const unsigned short* __restrict__ wkB, const float* __restrict__ bk,
    const float* __restrict__ bv, const float* __restrict__ bo,
    const unsigned short* __restrict__ wvT, const unsigned short* __restrict__ woT,
    float* __restrict__ ws_ne2)
{
    __shared__ unsigned short kA[64*LDK];     // ne (bf16) -> ctx (bf16)
    __shared__ unsigned short qkvT[16][EE];   // rows 8..15 zero
    __shared__ float ue[EE];
    __shared__ float qs[EE];
    __shared__ float qkb[HH];
    __shared__ float attn_s[HH][64];
    __shared__ float maskadd[64];

    const int b = blockIdx.x;
    const int t = threadIdx.x;

    // ---- gather phase ----
    if (t < EE) ue[t] = uet[(size_t)user[b]*EE + t];
    if (t >= 128 && t < 192) {
        const int s = t - 128;
        const bool real = (s < SS) && (neighbor[b*SS + s] > 0);
        maskadd[s] = real ? 0.f : -1e9f;
    }
    for (int idx = t; idx < SS*32; idx += 1024) {
        int s = idx >> 5, g = idx & 31;
        float4 v = ((const float4*)(uet + (size_t)neighbor[b*SS + s]*EE))[g];
        us4 o; o.x = f2bf(v.x); o.y = f2bf(v.y); o.z = f2bf(v.z); o.w = f2bf(v.w);
        *(us4*)&kA[s*LDK + g*4] = o;
    }
    for (int idx = t; idx < 14*LDK; idx += 1024) kA[50*LDK + idx] = 0;
    if (t < 8*EE) qkvT[8 + (t >> 7)][t & 127] = 0;
    __syncthreads();

    // ---- q = ue @ wq + bq (8 lanes per column), wq in bf16 ----
    {
        const int col = t >> 3, sub = t & 7;
        float acc = 0.f;
        #pragma unroll
        for (int d = 0; d < 16; ++d)
            acc = fmaf(ue[sub*16 + d], bf2f(wqB[(sub*16 + d)*EE + col]), acc);
        acc += __shfl_xor(acc, 1);
        acc += __shfl_xor(acc, 2);
        acc += __shfl_xor(acc, 4);
        if (sub == 0) qs[col] = acc + bq[col];
    }
    __syncthreads();

    // ---- qkvT[h][e] = q_h . Wk_h-block-row(e) ; qkb[h] = q_h . bk_h ; wk in bf16 ----
    {
        const int e = t >> 3, h = t & 7;
        const unsigned short* wrow = wkB + (size_t)e*EE + h*16;
        float acc = 0.f;
        #pragma unroll
        for (int d = 0; d < 16; ++d)
            acc = fmaf(qs[h*16 + d], bf2f(wrow[d]), acc);
        qkvT[h][e] = f2bf(acc);
    }
    if (t < HH) {
        float acc = 0.f;
        #pragma unroll
        for (int d = 0; d < 16; ++d) acc = fmaf(qs[t*16 + d], bk[t*16 + d], acc);
        qkb[t] = acc;
    }
    __syncthreads();

    const int w    = t >> 6;       // wave 0..15
    const int l    = t & 63;
    const int lrow = l & 15;
    const int kg   = l >> 4;
    const int rt   = w & 3;        // row-tile
    const int np   = w >> 2;       // nt-pair

    // ---- A fragments (ne rows of this wave's row-tile) ----
    bf16x8 a0 = *(const bf16x8*)&kA[(rt*16 + lrow)*LDK +  0 + kg*8];
    bf16x8 a1 = *(const bf16x8*)&kA[(rt*16 + lrow)*LDK + 32 + kg*8];
    bf16x8 a2 = *(const bf16x8*)&kA[(rt*16 + lrow)*LDK + 64 + kg*8];
    bf16x8 a3 = *(const bf16x8*)&kA[(rt*16 + lrow)*LDK + 96 + kg*8];

    // ---- logits via MFMA (waves 0..3 cover all 64 rows) ----
    if (np == 0) {
        bf16x8 b0 = *(const bf16x8*)&qkvT[lrow][ 0 + kg*8];
        bf16x8 b1 = *(const bf16x8*)&qkvT[lrow][32 + kg*8];
        bf16x8 b2 = *(const bf16x8*)&qkvT[lrow][64 + kg*8];
        bf16x8 b3 = *(const bf16x8*)&qkvT[lrow][96 + kg*8];
        f32x4 c = {0.f, 0.f, 0.f, 0.f};
        c = __builtin_amdgcn_mfma_f32_16x16x32_bf16(a0, b0, c, 0, 0, 0);
        c = __builtin_amdgcn_mfma_f32_16x16x32_bf16(a1, b1, c, 0, 0, 0);
        c = __builtin_amdgcn_mfma_f32_16x16x32_bf16(a2, b2, c, 0, 0, 0);
        c = __builtin_amdgcn_mfma_f32_16x16x32_bf16(a3, b3, c, 0, 0, 0);
        const int h = lrow;
        if (h < HH) {
            #pragma unroll
            for (int rg = 0; rg < 4; ++rg) {
                const int row = rt*16 + kg*4 + rg;
                attn_s[h][row] = (c[rg] + qkb[h]) * 0.25f + maskadd[row];
            }
        }
    }
    __syncthreads();

    // ---- softmax over s per head (one wave) ----
    if (t < 64) {
        int h = t >> 3, ll = t & 7;
        float mx = -3e38f;
        #pragma unroll
        for (int i = 0; i < 7; ++i) { int s = i*8 + ll; if (s < SS) mx = fmaxf(mx, attn_s[h][s]); }
        mx = fmaxf(mx, __shfl_xor(mx, 1));
        mx = fmaxf(mx, __shfl_xor(mx, 2));
        mx = fmaxf(mx, __shfl_xor(mx, 4));
        float ev[7]; float sm_ = 0.f;
        #pragma unroll
        for (int i = 0; i < 7; ++i) {
            int s = i*8 + ll; ev[i] = 0.f;
            if (s < SS) { ev[i] = expf(attn_s[h][s] - mx); sm_ += ev[i]; }
        }
        sm_ += __shfl_xor(sm_, 1);
        sm_ += __shfl_xor(sm_, 2);
        sm_ += __shfl_xor(sm_, 4);
        float inv = 1.f / sm_;
        #pragma unroll
        for (int i = 0; i < 7; ++i) { int s = i*8 + ll; if (s < SS) attn_s[h][s] = ev[i] * inv; }
    }
    __syncthreads();

    // ---- GEMM1: v = ne @ wv ; ctx = (v + bv) * attn -> bf16 into kA ----
    #pragma unroll
    for (int q = 0; q < 2; ++q) {
        const int nt = np*2 + q;
        const unsigned short* bp = wvT + (nt*16 + lrow)*EE + kg*8;
        bf16x8 b0 = *(const bf16x8*)&bp[0];
        bf16x8 b1 = *(const bf16x8*)&bp[32];
        bf16x8 b2 = *(const bf16x8*)&bp[64];
        bf16x8 b3 = *(const bf16x8*)&bp[96];
        f32x4 c = {0.f, 0.f, 0.f, 0.f};
        c = __builtin_amdgcn_mfma_f32_16x16x32_bf16(a0, b0, c, 0, 0, 0);
        c = __builtin_amdgcn_mfma_f32_16x16x32_bf16(a1, b1, c, 0, 0, 0);
        c = __builtin_amdgcn_mfma_f32_16x16x32_bf16(a2, b2, c, 0, 0, 0);
        c = __builtin_amdgcn_mfma_f32_16x16x32_bf16(a3, b3, c, 0, 0, 0);
        const int col = nt*16 + lrow;
        const float bvc = bv[col];
        #pragma unroll
        for (int rg = 0; rg < 4; ++rg) {
            const int row = rt*16 + kg*4 + rg;
            const float av = (row < SS) ? attn_s[nt][row] : 0.f;
            kA[row*LDK + col] = f2bf((c[rg] + bvc) * av);
        }
    }
    __syncthreads();

    // ---- GEMM2: ne2 = ctx @ wo + bo -> global ----
    bf16x8 c0 = *(const bf16x8*)&kA[(rt*16 + lrow)*LDK +  0 + kg*8];
    bf16x8 c1 = *(const bf16x8*)&kA[(rt*16 + lrow)*LDK + 32 + kg*8];
    bf16x8 c2 = *(const bf16x8*)&kA[(rt*16 + lrow)*LDK + 64 + kg*8];
    bf16x8 c3 = *(const bf16x8*)&kA[(rt*16 + lrow)*LDK + 96 + kg*8];

    #pragma unroll
    for (int q = 0; q < 2; ++q) {
        const int nt = np*2 + q;
        const unsigned short* bp = woT + (nt*16 + lrow)*EE + kg*8;
        bf16x8 b0 = *(const bf16x8*)&bp[0];
        bf16x8 b1 = *(const bf16x8*)&bp[32];
        bf16x8 b2 = *(const bf16x8*)&bp[64];
        bf16x8 b3 = *(const bf16x8*)&bp[96];
        f32x4 c = {0.f, 0.f, 0.f, 0.f};
        c = __builtin_amdgcn_mfma_f32_16x16x32_bf16(c0, b0, c, 0, 0, 0);
        c = __builtin_amdgcn_mfma_f32_16x16x32_bf16(c1, b1, c, 0, 0, 0);
        c = __builtin_amdgcn_mfma_f32_16x16x32_bf16(c2, b2, c, 0, 0, 0);
        c = __builtin_amdgcn_mfma_f32_16x16x32_bf16(c3, b3, c, 0, 0, 0);
        const int col = nt*16 + lrow;
        const float boc = bo[col];
        #pragma unroll
        for (int rg = 0; rg < 4; ++rg) {
            const int row = rt*16 + kg*4 + rg;
            if (row < SS)
                ws_ne2[((size_t)b*SS + row)*EE + col] = c[rg] + boc;
        }
    }
}

// -------------------- Kernel 2: per-unique-j region + fused s-max (atomicMax) -----------
__global__ __launch_bounds__(256, 6) void region_kernel(
    const int* __restrict__ neighbor, const int* __restrict__ item,
    const float* __restrict__ ui_lcu, const float* __restrict__ iu_lcu,
    const float* __restrict__ iet, const float* __restrict__ ws_ne2,
    const int* __restrict__ hstart, const int* __restrict__ perm,
    unsigned* __restrict__ umax)
{
    const int j = blockIdx.x;
    const int start = hstart[j];
    const int end   = hstart[j + 1];
    if (start >= end) return;

    const int t = threadIdx.x;
    const int r = t >> 3, l = t & 7;

    const f32x4* kiu_g = (const f32x4*)(iu_lcu + ((size_t)j*RR + r)*EE);
    const f32x4* kui_g = (const f32x4*)(ui_lcu + ((size_t)j*RR + r)*EE);
    f32x4 kiu_r[4], kui_r[4];
    #pragma unroll
    for (int i = 0; i < 4; ++i) {
        kiu_r[i] = __builtin_nontemporal_load(&kiu_g[l + 8*i]);
        kui_r[i] = __builtin_nontemporal_load(&kui_g[l + 8*i]);
    }

    for (int o = start; o < end; ++o) {
        const int bs = perm[o];
        const int b  = (unsigned)bs / SS;
        const float4* n4 = (const float4*)(ws_ne2 + (size_t)bs*EE);
        const float4* i4 = (const float4*)(iet + (size_t)item[b]*EE);

        float np_ = 0.f, ip_ = 0.f;
        #pragma unroll
        for (int i = 0; i < 4; ++i) {
            int c = l + 8*i;
            np_ += dot4v(kiu_r[i], n4[c]);
            ip_ += dot4v(kui_r[i], i4[c]);
        }
        np_ += __shfl_xor(np_, 1); np_ += __shfl_xor(np_, 2); np_ += __shfl_xor(np_, 4);
        ip_ += __shfl_xor(ip_, 1); ip_ += __shfl_xor(ip_, 2); ip_ += __shfl_xor(ip_, 4);

        const float w = (neighbor[bs] > 0) ? 1.f : 0.f;
        if (l == 0)
            atomicMax(&umax[(size_t)b*RR + r], fmap(np_ * ip_ * w));
    }
}

// -------------------- Kernel 3: unmap, FC, softmax --------------------
__global__ __launch_bounds__(64) void head_kernel(
    const unsigned* __restrict__ umax,
    const float* __restrict__ fc_w, const float* __restrict__ fc_b,
    float* __restrict__ out)
{
    __shared__ float urv[RR];
    __shared__ float lg[NC];
    const int b = blockIdx.x, t = threadIdx.x;

    if (t < RR) urv[t] = funmap(umax[(size_t)b*RR + t]);
    __syncthreads();
    if (t < NC) {
        float acc = fc_b[t];
        #pragma unroll
        for (int rr = 0; rr < RR; ++rr) acc = fmaf(urv[rr], fc_w[rr*NC + t], acc);
        lg[t] = acc;
    }
    __syncthreads();
    if (t < NC) {
        float mx = lg[0];
        #pragma unroll
        for (int c = 1; c < NC; ++c) mx = fmaxf(mx, lg[c]);
        float sm = 0.f;
        #pragma unroll
        for (int c = 0; c < NC; ++c) sm += expf(lg[c] - mx);
        out[b*NC + t] = expf(lg[t] - mx) / sm;
    }
}

extern "C" void kernel_launch(void* const* d_in, const int* in_sizes, int n_in,
                              void* d_out, int out_size, void* d_ws, size_t ws_size,
                              hipStream_t stream) {
    const int*   user     = (const int*)d_in[0];
    const int*   item     = (const int*)d_in[1];
    const int*   neighbor = (const int*)d_in[2];
    const int*   seq      = (const int*)d_in[3];
    const float* uet      = (const float*)d_in[4];
    const float* iet      = (const float*)d_in[5];
    const float* ui_lcu   = (const float*)d_in[6];
    const float* iu_lcu   = (const float*)d_in[7];
    const float* wq = (const float*)d_in[8];   const float* bq = (const float*)d_in[9];
    const float* wk = (const float*)d_in[10];  const float* bk = (const float*)d_in[11];
    const float* wv = (const float*)d_in[12];  const float* bv = (const float*)d_in[13];
    const float* wo = (const float*)d_in[14];  const float* bo = (const float*)d_in[15];
    const float* fcw = (const float*)d_in[16]; const float* fcb = (const float*)d_in[17];

    float* ws = (float*)d_ws;
    float* ws_ne2 = ws;                                          // B*S*E f32
    unsigned short* wvT = (unsigned short*)(ws_ne2 + (size_t)BB*SS*EE);  // 128*128 bf16
    unsigned short* woT = wvT + EE*EE;                           // 128*128 bf16
    unsigned short* wqB = woT + EE*EE;                           // 128*128 bf16
    unsigned short* wkB = wqB + EE*EE;                           // 128*128 bf16
    int*      hist   = (int*)(wkB + EE*EE);                      // NSEQ
    unsigned* umax   = (unsigned*)(hist + NSEQ);                 // BB*RR (mapped floats)
    int*      hstart = (int*)(umax + (size_t)BB*RR);             // NSEQ+1
    int*      perm   = hstart + NSEQ + 1;                        // NBS
    float* out = (float*)d_out;

    // ---- prep: transposes/copies + hist (fused), scan, scatter; zero hist+umax ----
    hipMemsetAsync(hist, 0, (NSEQ + BB*RR) * sizeof(int), stream);
    hipLaunchKernelGGL(prep_kernel, dim3(192 + (NBS + 255)/256), dim3(256), 0, stream,
                       wv, wo, wq, wk, wvT, woT, wqB, wkB, seq, hist);
    hipLaunchKernelGGL(scan_kernel, dim3(1), dim3(1024), 0, stream, hist, hstart);
    hipLaunchKernelGGL(scatter_kernel, dim3((NBS + 255)/256), dim3(256), 0, stream,
                       seq, hist, perm);

    // ---- attention (all-MFMA, 1024-thread blocks, bf16 weight streams) ----
    hipLaunchKernelGGL(attn_kernel, dim3(BB), dim3(1024), 0, stream,
                       user, neighbor, uet,
                       wqB, bq, wkB, bk, bv, bo, wvT, woT, ws_ne2);

    // ---- region + fused max ----
    hipLaunchKernelGGL(region_kernel, dim3(NSEQ), dim3(256), 0, stream,
                       neighbor, item, ui_lcu, iu_lcu, iet, ws_ne2, hstart, perm, umax);

    hipLaunchKernelGGL(head_kernel, dim3(BB), dim3(64), 0, stream,
                       umax, fcw, fcb, out);
}